// Round 1
// baseline (72.483 us; speedup 1.0000x reference)
//
#include <hip/hip_runtime.h>
#include <hip/hip_bf16.h>

#define W_OUT 768
#define H_OUT 768
#define N_PIX (W_OUT * H_OUT)
#define N_BOX 64
#define PPT 4  // pixels per thread in the scan kernel

// ws layout:
//   [0, 6144)       row_mask: uint64[768]
//   [6144, 12288)   col_mask: uint64[768]  (area_ok folded in)
//   [12288, 12544)  scores:   uint32[64]   (float bits, monotone for >=0)

__global__ __launch_bounds__(256) void build_masks_kernel(
    const float* __restrict__ boxes,
    unsigned long long* __restrict__ row_mask,
    unsigned long long* __restrict__ col_mask,
    unsigned int* __restrict__ scores) {
  __shared__ float bx1[N_BOX], by1[N_BOX], bx2[N_BOX], by2[N_BOX];
  __shared__ unsigned long long area_sh;
  const int tid = threadIdx.x;

  if (tid < N_BOX) {  // exactly wave 0
    const float x1 = boxes[tid * 5 + 0];
    const float y1 = boxes[tid * 5 + 1];
    const float x2 = boxes[tid * 5 + 2];
    const float y2 = boxes[tid * 5 + 3];
    bx1[tid] = x1; by1[tid] = y1; bx2[tid] = x2; by2[tid] = y2;
    const bool ok = ((x2 - x1) * (y2 - y1)) != 0.0f;
    const unsigned long long am = __ballot(ok);
    if (tid == 0) area_sh = am;
    scores[tid] = 0u;  // init score buffer (ws is poisoned each run)
  }
  __syncthreads();
  const unsigned long long area = area_sh;

  for (int i = tid; i < W_OUT; i += 256) {
    const float c = (float)i * 2.0f + 1.0f;  // STRIDE*i + STRIDE/2
    unsigned long long rm = 0ull, cm = 0ull;
#pragma unroll
    for (int n = 0; n < N_BOX; ++n) {
      if (c >= by1[n] && c <= by2[n]) rm |= (1ull << n);
      if (c >= bx1[n] && c <= bx2[n]) cm |= (1ull << n);
    }
    row_mask[i] = rm;
    col_mask[i] = cm & area;  // fold area_ok into columns
  }
}

__global__ __launch_bounds__(256) void score_pixels_kernel(
    const float* __restrict__ conf,
    const unsigned long long* __restrict__ row_mask,
    const unsigned long long* __restrict__ col_mask,
    unsigned int* __restrict__ scores) {
  __shared__ unsigned int smax[N_BOX];
  const int tid = threadIdx.x;
  if (tid < N_BOX) smax[tid] = 0u;
  __syncthreads();

  const int base = blockIdx.x * (256 * PPT) + tid;
#pragma unroll
  for (int k = 0; k < PPT; ++k) {
    const int idx = base + k * 256;  // grid sized to cover N_PIX exactly
    const int h = idx / W_OUT;
    const int w = idx - h * W_OUT;
    const unsigned long long m = row_mask[h] & col_mask[w];
    if (__popcll(m) == 1) {
      const int n = __ffsll((unsigned long long)m) - 1;
      const float x = conf[idx];
      const float s = 1.0f / (1.0f + __expf(-x));  // sigmoid, (0,1) so bits are order-preserving
      atomicMax(&smax[n], __float_as_uint(s));
    }
  }
  __syncthreads();
  if (tid < N_BOX) {
    const unsigned int v = smax[tid];
    if (v) atomicMax(&scores[tid], v);  // skip global atomic for empty blocks
  }
}

__global__ __launch_bounds__(64) void finalize_kernel(
    const unsigned int* __restrict__ scores, float* __restrict__ out) {
  const int n = threadIdx.x;
  const unsigned int v = scores[n];
  out[n] = __uint_as_float(v);
  out[N_BOX + n] = (v != 0u) ? 1.0f : 0.0f;  // valid = mask.any() (sigmoid > 0 always)
}

extern "C" void kernel_launch(void* const* d_in, const int* in_sizes, int n_in,
                              void* d_out, int out_size, void* d_ws, size_t ws_size,
                              hipStream_t stream) {
  const float* conf = (const float*)d_in[0];
  const float* bboxes = (const float*)d_in[2];  // [x1,y1,x2,y2,cls] x 64
  float* out = (float*)d_out;

  char* ws = (char*)d_ws;
  unsigned long long* row_mask = (unsigned long long*)(ws);
  unsigned long long* col_mask = (unsigned long long*)(ws + 6144);
  unsigned int* scores = (unsigned int*)(ws + 12288);

  build_masks_kernel<<<1, 256, 0, stream>>>(bboxes, row_mask, col_mask, scores);
  score_pixels_kernel<<<N_PIX / (256 * PPT), 256, 0, stream>>>(conf, row_mask, col_mask, scores);
  finalize_kernel<<<1, 64, 0, stream>>>(scores, out);
}